// Round 6
// baseline (537.032 us; speedup 1.0000x reference)
//
#include <hip/hip_runtime.h>
#include <hip/hip_bf16.h>

// Linear: C[M,N] = A[M,K] @ W[N,K]^T + bias[N]. fp32 in/out (harness maps fp16
// reference -> fp32 buffers), bf16 MFMA compute (2% threshold).
//
// Round 6: revert to round-4 tile geometry (128x128, BK=64, 16x16x32, 0-conflict
// swizzle, 259 us) and attack the barrier-drain stall:
//  - GEMM: double-buffered LDS (STATIC arrays sA0/sA1 so alias analysis keeps
//    vmcnt waits off the ds_reads), K-loop unrolled x2, global_load_lds
//    prefetch for tile k+1 issued BEFORE compute on tile k. The vmcnt(0) at
//    each __syncthreads now drains loads that had a full compute phase to
//    land. One barrier per k-tile (was 2). Nontemporal C stores.
//  - PACK: nontemporal fp32 loads (inputs never re-read; keep packed bf16
//    resident in L2/L3), 2 chunks/thread ILP, 128-row tile layout w/ XOR
//    chunk swizzle cp = sc ^ (row&7).

typedef unsigned short u16;
typedef unsigned int u32;
typedef __bf16 bf16x8 __attribute__((ext_vector_type(8)));
typedef float f32x4 __attribute__((ext_vector_type(4)));
typedef u32 u32x4 __attribute__((ext_vector_type(4)));

#define M_DIM 8192
#define N_DIM 4096
#define K_DIM 4096
#define BM 128
#define BN 128
#define BK 64

#define KT (K_DIM / BK)                 // 64 k-tiles
#define TILE_ELEMS (BM * BK)            // 8192 elems / tile (A and W same)
#define TILE_CH (TILE_ELEMS / 8)        // 1024 16B-chunks / tile
#define A_CHUNKS ((M_DIM / BM) * KT * TILE_CH)   // 4,194,304
#define W_CHUNKS ((N_DIM / BN) * KT * TILE_CH)   // 2,097,152
#define A_PACK_BYTES ((size_t)A_CHUNKS * 16)     // 64 MiB
#define W_PACK_BYTES ((size_t)W_CHUNKS * 16)     // 32 MiB

// pack two fp32 -> (bf16(hi)<<16)|bf16(lo) by byte-perm truncation
__device__ __forceinline__ u32 pack2bf(float lo, float hi) {
    return __builtin_amdgcn_perm(__float_as_uint(hi), __float_as_uint(lo),
                                 0x07060302u);
}

__device__ __forceinline__ void g2l16(const u16* g, __bf16* l) {
    __builtin_amdgcn_global_load_lds((__attribute__((address_space(1))) void*)g,
                                     (__attribute__((address_space(3))) void*)l,
                                     16, 0, 0);
}

// ---------------- Phase 1: convert + tile-pack + swizzle ----------------
// Thread handles 2 consecutive source chunks (64 B contiguous NT read);
// writes land at cp = sc ^ (row&7), adjacent pair cp^1 (sc even).
__global__ __launch_bounds__(256) void pack_bf16_kernel(
    const float* __restrict__ A, const float* __restrict__ W,
    u32x4* __restrict__ aP, u32x4* __restrict__ wP)
{
    const long t = (long)blockIdx.x * 256 + threadIdx.x;
    const long cid = t * 2;

    const float* src;
    u32x4* dst;
    long id;
    if (cid < (long)A_CHUNKS) { id = cid;            src = A; dst = aP; }
    else                      { id = cid - A_CHUNKS; src = W; dst = wP; }

    const int tile = (int)(id >> 10);          // 1024 chunks/tile
    const int slot = (int)(id & 1023);
    const int row  = slot >> 3;                // 0..127
    const int sc   = slot & 7;                 // even (2 chunks/thread)
    const int rb   = tile >> 6;                // row-block (mt or nt)
    const int kt   = tile & (KT - 1);

    const float* p = src + (size_t)(rb * BM + row) * K_DIM + kt * BK + sc * 8;
    f32x4 v0 = __builtin_nontemporal_load((const f32x4*)(p));
    f32x4 v1 = __builtin_nontemporal_load((const f32x4*)(p + 4));
    f32x4 v2 = __builtin_nontemporal_load((const f32x4*)(p + 8));
    f32x4 v3 = __builtin_nontemporal_load((const f32x4*)(p + 12));

    const long tbase = ((long)tile << 10) + row * 8;
    const int cp0 = sc ^ (row & 7);
    dst[tbase + cp0] = u32x4{pack2bf(v0[0], v0[1]), pack2bf(v0[2], v0[3]),
                             pack2bf(v1[0], v1[1]), pack2bf(v1[2], v1[3])};
    dst[tbase + (cp0 ^ 1)] = u32x4{pack2bf(v2[0], v2[1]), pack2bf(v2[2], v2[3]),
                                   pack2bf(v3[0], v3[1]), pack2bf(v3[2], v3[3])};
}

// ---------------- Phase 2: GEMM, double-buffered prefetch pipeline ----------
__shared__ __attribute__((aligned(16))) __bf16 sA0[TILE_ELEMS];
__shared__ __attribute__((aligned(16))) __bf16 sB0[TILE_ELEMS];
__shared__ __attribute__((aligned(16))) __bf16 sA1[TILE_ELEMS];
__shared__ __attribute__((aligned(16))) __bf16 sB1[TILE_ELEMS];

__global__ __launch_bounds__(256, 2) void gemm_packed_kernel(
    const u16* __restrict__ aP,      // packed A tiles (128x64, swizzled)
    const u16* __restrict__ wP,      // packed W tiles (128x64, swizzled)
    const float* __restrict__ bias,  // [N] fp32
    float* __restrict__ C)           // [M, N] fp32
{
    const int tid  = threadIdx.x;
    const int lane = tid & 63;
    const int wave = tid >> 6;
    const int quad = lane >> 4;
    const int l16  = lane & 15;
    const int wm   = wave >> 1;       // 2x2 wave grid, wave tile 64x64
    const int wn   = wave & 1;

    const int bn = blockIdx.x;        // 32 N-tiles
    const int bm = blockIdx.y;        // 64 M-tiles

    const u16* aT = aP + (size_t)bm * KT * TILE_ELEMS + tid * 8;
    const u16* wT = wP + (size_t)bn * KT * TILE_ELEMS + tid * 8;

    f32x4 acc[4][4];
#pragma unroll
    for (int i = 0; i < 4; ++i)
#pragma unroll
        for (int j = 0; j < 4; ++j)
            acc[i][j] = f32x4{0.f, 0.f, 0.f, 0.f};

    const int aRow = wm * 64 + l16;   // + mi*16
    const int bRow = wn * 64 + l16;   // + ni*16
    const int cswz = l16 & 7;         // row&7 (wm*64, mi*16 keep low 3 bits)

    // stage tile kt into (dA, dB): 4+4 async 16B chunks per thread
#define STAGE(kt_, dA, dB)                                         \
    {                                                              \
        const size_t tb_ = (size_t)(kt_)*TILE_ELEMS;               \
        _Pragma("unroll") for (int it = 0; it < 4; ++it) {         \
            g2l16(aT + tb_ + it * 2048, &(dA)[tid * 8 + it * 2048]); \
            g2l16(wT + tb_ + it * 2048, &(dB)[tid * 8 + it * 2048]); \
        }                                                          \
    }

    // compute one k-tile from (bA, bB): 2 k-steps x 16 MFMA
#define COMPUTE(bA, bB)                                                   \
    {                                                                     \
        _Pragma("unroll") for (int ks8 = 0; ks8 < 8; ks8 += 4) {          \
            const int cp = (quad + ks8) ^ cswz;                           \
            bf16x8 af[4], bfr[4];                                         \
            _Pragma("unroll") for (int mi = 0; mi < 4; ++mi)              \
                af[mi] = *(const bf16x8*)&(bA)[(aRow + mi * 16) * BK + cp * 8]; \
            _Pragma("unroll") for (int ni = 0; ni < 4; ++ni)              \
                bfr[ni] = *(const bf16x8*)&(bB)[(bRow + ni * 16) * BK + cp * 8]; \
            _Pragma("unroll") for (int mi = 0; mi < 4; ++mi)              \
                _Pragma("unroll") for (int ni = 0; ni < 4; ++ni)          \
                    acc[mi][ni] = __builtin_amdgcn_mfma_f32_16x16x32_bf16(  \
                        af[mi], bfr[ni], acc[mi][ni], 0, 0, 0);           \
        }                                                                 \
    }

    // prologue: stage tile 0 into buffer 0
    STAGE(0, sA0, sB0);

    for (int kt = 0; kt < KT; kt += 2) {
        __syncthreads();              // drains prefetch issued a full phase ago
        STAGE(kt + 1, sA1, sB1);      // prefetch next tile BEFORE compute
        COMPUTE(sA0, sB0);
        __syncthreads();
        if (kt + 2 < KT) STAGE(kt + 2, sA0, sB0);
        COMPUTE(sA1, sB1);
    }
#undef STAGE
#undef COMPUTE

    // epilogue: C/D col = lane&15, row = quad*4 + reg; fp32 + bias, NT stores
    const int colBase = bn * BN + wn * 64 + l16;
    const int rowBase = bm * BM + wm * 64 + quad * 4;
#pragma unroll
    for (int ni = 0; ni < 4; ++ni) {
        const int col = colBase + ni * 16;
        const float bv = bias[col];
#pragma unroll
        for (int mi = 0; mi < 4; ++mi) {
            const int row = rowBase + mi * 16;
#pragma unroll
            for (int r = 0; r < 4; ++r)
                __builtin_nontemporal_store(acc[mi][ni][r] + bv,
                                            &C[(size_t)(row + r) * N_DIM + col]);
        }
    }
}

// ---------------- Fallback (round-3 kernel, ws too small) ----------------
__global__ __launch_bounds__(256, 2) void linear_f32_bf16mfma_kernel(
    const float* __restrict__ A, const float* __restrict__ W,
    const float* __restrict__ bias, float* __restrict__ C)
{
    __shared__ __attribute__((aligned(16))) __bf16 sA[128 * 64];
    __shared__ __attribute__((aligned(16))) __bf16 sB[128 * 64];

    const int tid  = threadIdx.x;
    const int lane = tid & 63;
    const int wave = tid >> 6;
    const int quad = lane >> 4;
    const int l16  = lane & 15;
    const int wm   = wave >> 1;
    const int wn   = wave & 1;
    const int bn = blockIdx.x;
    const int bm = blockIdx.y;
    const int srow = tid >> 3;
    const int scol = (tid & 7) * 8;

    const float* aBase = A + (size_t)(bm * 128 + srow) * K_DIM + scol;
    const float* bBase = W + (size_t)(bn * 128 + srow) * K_DIM + scol;

    f32x4 acc[4][4];
#pragma unroll
    for (int i = 0; i < 4; ++i)
#pragma unroll
        for (int j = 0; j < 4; ++j)
            acc[i][j] = f32x4{0.f, 0.f, 0.f, 0.f};

    const int aRow = wm * 64 + l16;
    const int bRow = wn * 64 + l16;
    const int kOff = quad * 8;

    for (int k0 = 0; k0 < K_DIM; k0 += 64) {
        f32x4 ga[4][2], gb[4][2];
#pragma unroll
        for (int it = 0; it < 4; ++it) {
            const float* pa = aBase + (size_t)(it * 32) * K_DIM + k0;
            const float* pb = bBase + (size_t)(it * 32) * K_DIM + k0;
            ga[it][0] = *(const f32x4*)(pa);
            ga[it][1] = *(const f32x4*)(pa + 4);
            gb[it][0] = *(const f32x4*)(pb);
            gb[it][1] = *(const f32x4*)(pb + 4);
        }
        u32x4 wa[4], wb[4];
#pragma unroll
        for (int it = 0; it < 4; ++it) {
            wa[it] = u32x4{pack2bf(ga[it][0][0], ga[it][0][1]),
                           pack2bf(ga[it][0][2], ga[it][0][3]),
                           pack2bf(ga[it][1][0], ga[it][1][1]),
                           pack2bf(ga[it][1][2], ga[it][1][3])};
            wb[it] = u32x4{pack2bf(gb[it][0][0], gb[it][0][1]),
                           pack2bf(gb[it][0][2], gb[it][0][3]),
                           pack2bf(gb[it][1][0], gb[it][1][1]),
                           pack2bf(gb[it][1][2], gb[it][1][3])};
        }
        __syncthreads();
#pragma unroll
        for (int it = 0; it < 4; ++it) {
            *(u32x4*)&sA[tid * 8 + it * 2048] = wa[it];
            *(u32x4*)&sB[tid * 8 + it * 2048] = wb[it];
        }
        __syncthreads();
#pragma unroll
        for (int ks = 0; ks < 64; ks += 32) {
            bf16x8 af[4], bfr[4];
#pragma unroll
            for (int mi = 0; mi < 4; ++mi)
                af[mi] = *(const bf16x8*)&sA[(aRow + mi * 16) * 64 + ks + kOff];
#pragma unroll
            for (int ni = 0; ni < 4; ++ni)
                bfr[ni] = *(const bf16x8*)&sB[(bRow + ni * 16) * 64 + ks + kOff];
#pragma unroll
            for (int mi = 0; mi < 4; ++mi)
#pragma unroll
                for (int ni = 0; ni < 4; ++ni)
                    acc[mi][ni] = __builtin_amdgcn_mfma_f32_16x16x32_bf16(
                        af[mi], bfr[ni], acc[mi][ni], 0, 0, 0);
        }
    }
    const int colBase = bn * 128 + wn * 64 + l16;
    const int rowBase = bm * 128 + wm * 64 + quad * 4;
#pragma unroll
    for (int ni = 0; ni < 4; ++ni) {
        const int col = colBase + ni * 16;
        const float bv = bias[col];
#pragma unroll
        for (int mi = 0; mi < 4; ++mi) {
            const int row = rowBase + mi * 16;
#pragma unroll
            for (int r = 0; r < 4; ++r)
                C[(size_t)(row + r) * N_DIM + col] = acc[mi][ni][r] + bv;
        }
    }
}

extern "C" void kernel_launch(void* const* d_in, const int* in_sizes, int n_in,
                              void* d_out, int out_size, void* d_ws, size_t ws_size,
                              hipStream_t stream) {
    const float* x = (const float*)d_in[0];   // [8192, 4096]
    const float* w = (const float*)d_in[1];   // [4096, 4096]
    const float* b = (const float*)d_in[2];   // [4096]
    float* out = (float*)d_out;

    if (ws_size >= A_PACK_BYTES + W_PACK_BYTES) {
        u32x4* aP = (u32x4*)d_ws;
        u32x4* wP = (u32x4*)((char*)d_ws + A_PACK_BYTES);
        const long total_threads = (long)(A_CHUNKS + W_CHUNKS) / 2;
        pack_bf16_kernel<<<(int)(total_threads / 256), 256, 0, stream>>>(x, w, aP, wP);
        dim3 grid(N_DIM / BN, M_DIM / BM);    // (32, 64) = 2048 blocks
        gemm_packed_kernel<<<grid, 256, 0, stream>>>(
            (const u16*)aP, (const u16*)wP, b, out);
    } else {
        dim3 grid(N_DIM / 128, M_DIM / 128);
        linear_f32_bf16mfma_kernel<<<grid, 256, 0, stream>>>(x, w, b, out);
    }
}

// Round 7
// 497.460 us; speedup vs baseline: 1.0795x; 1.0795x over previous
//
#include <hip/hip_runtime.h>
#include <hip/hip_bf16.h>

// Linear: C[M,N] = A[M,K] @ W[N,K]^T + bias[N]. fp32 in/out (harness maps fp16
// reference -> fp32 buffers), bf16 MFMA compute (2% threshold).
//
// Round 7: revert to round-4 gemm (128x128, BK=64, single-buffer, swizzled,
// 259 us measured) with ONE change: __launch_bounds__(256, 4) — round-4 ran
// 3 blocks/CU only because I asked for 3; regs (56 VGPR + 64 AGPR = 120) and
// LDS (32 KiB) both permit 4. LDS-pipe floor is ~165 us; more resident
// blocks = better stall coverage toward it.
// Pack: round-4 addressing (swizzle-on-read within 128B lines -> coalesced;
// linear 16B writes) + nontemporal input loads (round-6 showed FETCH 508->378).

typedef unsigned short u16;
typedef unsigned int u32;
typedef __bf16 bf16x8 __attribute__((ext_vector_type(8)));
typedef float f32x4 __attribute__((ext_vector_type(4)));
typedef u32 u32x4 __attribute__((ext_vector_type(4)));

#define M_DIM 8192
#define N_DIM 4096
#define K_DIM 4096
#define BM 128
#define BN 128
#define BK 64

#define KT (K_DIM / BK)                 // 64 k-tiles
#define TILE_ELEMS (BM * BK)            // 8192 elems / tile
#define A_CHUNKS ((M_DIM / BM) * KT * (TILE_ELEMS / 8))   // 4,194,304
#define W_CHUNKS ((N_DIM / BN) * KT * (TILE_ELEMS / 8))   // 2,097,152
#define A_PACK_BYTES ((size_t)A_CHUNKS * 16)              // 64 MiB
#define W_PACK_BYTES ((size_t)W_CHUNKS * 16)              // 32 MiB

// pack two fp32 -> (bf16(hi)<<16)|bf16(lo) by byte-perm truncation
__device__ __forceinline__ u32 pack2bf(float lo, float hi) {
    return __builtin_amdgcn_perm(__float_as_uint(hi), __float_as_uint(lo),
                                 0x07060302u);
}

__device__ __forceinline__ void g2l16(const u16* g, __bf16* l) {
    __builtin_amdgcn_global_load_lds((__attribute__((address_space(1))) void*)g,
                                     (__attribute__((address_space(3))) void*)l,
                                     16, 0, 0);
}

// ---------------- Phase 1: convert + tile-pack + swizzle ----------------
// One thread per 16B packed chunk; source chunk = phys ^ (row&7) (within the
// row's 128B line -> wave reads whole lines, permuted; writes fully linear).
__global__ __launch_bounds__(256) void pack_bf16_kernel(
    const float* __restrict__ A, const float* __restrict__ W,
    u32x4* __restrict__ aP, u32x4* __restrict__ wP)
{
    int gid = blockIdx.x * 256 + threadIdx.x;
    const float* src;
    u32x4* dst;
    int id;
    if (gid < A_CHUNKS) { src = A; dst = aP; id = gid; }
    else                { src = W; dst = wP; id = gid - A_CHUNKS; }

    const int tile = id >> 10;         // 1024 chunks per tile
    const int slot = id & 1023;
    const int row  = slot >> 3;        // 0..127
    const int cp   = slot & 7;         // physical chunk in packed layout
    const int rb   = tile >> 6;        // row-block (mt or nt)
    const int kt   = tile & (KT - 1);
    const int sc   = cp ^ (row & 7);   // source (logical) chunk

    const float* p = src + (size_t)(rb * BM + row) * K_DIM + kt * BK + sc * 8;
    f32x4 v0 = __builtin_nontemporal_load((const f32x4*)(p));
    f32x4 v1 = __builtin_nontemporal_load((const f32x4*)(p + 4));
    dst[id] = u32x4{pack2bf(v0[0], v0[1]), pack2bf(v0[2], v0[3]),
                    pack2bf(v1[0], v1[1]), pack2bf(v1[2], v1[3])};
}

// ---------------- Phase 2: GEMM from packed bf16 (round-4 structure) --------
__global__ __launch_bounds__(256, 4) void gemm_packed_kernel(
    const u16* __restrict__ aP,      // packed A tiles (128x64, swizzled)
    const u16* __restrict__ wP,      // packed W tiles (128x64, swizzled)
    const float* __restrict__ bias,  // [N] fp32
    float* __restrict__ C)           // [M, N] fp32
{
    __shared__ __attribute__((aligned(16))) __bf16 sA[TILE_ELEMS];
    __shared__ __attribute__((aligned(16))) __bf16 sB[TILE_ELEMS];

    const int tid  = threadIdx.x;
    const int lane = tid & 63;
    const int wave = tid >> 6;
    const int quad = lane >> 4;
    const int l16  = lane & 15;
    const int wm   = wave >> 1;       // 2x2 wave grid, wave tile 64x64
    const int wn   = wave & 1;

    const int bn = blockIdx.x;        // 32 N-tiles
    const int bm = blockIdx.y;        // 64 M-tiles

    const u16* aT = aP + (size_t)bm * KT * TILE_ELEMS + tid * 8;
    const u16* wT = wP + (size_t)bn * KT * TILE_ELEMS + tid * 8;
    __bf16* sAp = &sA[tid * 8];
    __bf16* sBp = &sB[tid * 8];

    f32x4 acc[4][4];
#pragma unroll
    for (int i = 0; i < 4; ++i)
#pragma unroll
        for (int j = 0; j < 4; ++j)
            acc[i][j] = f32x4{0.f, 0.f, 0.f, 0.f};

    const int aRow = wm * 64 + l16;   // + mi*16
    const int bRow = wn * 64 + l16;   // + ni*16
    const int cswz = l16 & 7;         // row&7 (wm*64, mi*16 keep low 3 bits)

    for (int kt = 0; kt < KT; ++kt) {
        const size_t tb = (size_t)kt * TILE_ELEMS;
#pragma unroll
        for (int it = 0; it < 4; ++it) {
            g2l16(aT + tb + it * 2048, sAp + it * 2048);
            g2l16(wT + tb + it * 2048, sBp + it * 2048);
        }
        __builtin_amdgcn_s_waitcnt(0);   // drain vmcnt before barrier
        __syncthreads();

#pragma unroll
        for (int ks8 = 0; ks8 < 8; ks8 += 4) {      // ks = ks8*8 in {0,32}
            const int cp = (quad + ks8) ^ cswz;      // physical chunk
            bf16x8 af[4], bfr[4];
#pragma unroll
            for (int mi = 0; mi < 4; ++mi)
                af[mi] = *(const bf16x8*)&sA[(aRow + mi * 16) * BK + cp * 8];
#pragma unroll
            for (int ni = 0; ni < 4; ++ni)
                bfr[ni] = *(const bf16x8*)&sB[(bRow + ni * 16) * BK + cp * 8];
#pragma unroll
            for (int mi = 0; mi < 4; ++mi)
#pragma unroll
                for (int ni = 0; ni < 4; ++ni)
                    acc[mi][ni] = __builtin_amdgcn_mfma_f32_16x16x32_bf16(
                        af[mi], bfr[ni], acc[mi][ni], 0, 0, 0);
        }
        __syncthreads();
    }

    // epilogue: C/D layout col = lane&15, row = quad*4 + reg; fp32 out + bias
    const int colBase = bn * BN + wn * 64 + l16;
    const int rowBase = bm * BM + wm * 64 + quad * 4;
#pragma unroll
    for (int ni = 0; ni < 4; ++ni) {
        const int col = colBase + ni * 16;
        const float bv = bias[col];
#pragma unroll
        for (int mi = 0; mi < 4; ++mi) {
            const int row = rowBase + mi * 16;
#pragma unroll
            for (int r = 0; r < 4; ++r)
                C[(size_t)(row + r) * N_DIM + col] = acc[mi][ni][r] + bv;
        }
    }
}

// ---------------- Fallback (round-3 kernel, ws too small) ----------------
__global__ __launch_bounds__(256, 2) void linear_f32_bf16mfma_kernel(
    const float* __restrict__ A, const float* __restrict__ W,
    const float* __restrict__ bias, float* __restrict__ C)
{
    __shared__ __attribute__((aligned(16))) __bf16 sA[128 * 64];
    __shared__ __attribute__((aligned(16))) __bf16 sB[128 * 64];

    const int tid  = threadIdx.x;
    const int lane = tid & 63;
    const int wave = tid >> 6;
    const int quad = lane >> 4;
    const int l16  = lane & 15;
    const int wm   = wave >> 1;
    const int wn   = wave & 1;
    const int bn = blockIdx.x;
    const int bm = blockIdx.y;
    const int srow = tid >> 3;
    const int scol = (tid & 7) * 8;

    const float* aBase = A + (size_t)(bm * 128 + srow) * K_DIM + scol;
    const float* bBase = W + (size_t)(bn * 128 + srow) * K_DIM + scol;

    f32x4 acc[4][4];
#pragma unroll
    for (int i = 0; i < 4; ++i)
#pragma unroll
        for (int j = 0; j < 4; ++j)
            acc[i][j] = f32x4{0.f, 0.f, 0.f, 0.f};

    const int aRow = wm * 64 + l16;
    const int bRow = wn * 64 + l16;
    const int kOff = quad * 8;

    for (int k0 = 0; k0 < K_DIM; k0 += 64) {
        f32x4 ga[4][2], gb[4][2];
#pragma unroll
        for (int it = 0; it < 4; ++it) {
            const float* pa = aBase + (size_t)(it * 32) * K_DIM + k0;
            const float* pb = bBase + (size_t)(it * 32) * K_DIM + k0;
            ga[it][0] = *(const f32x4*)(pa);
            ga[it][1] = *(const f32x4*)(pa + 4);
            gb[it][0] = *(const f32x4*)(pb);
            gb[it][1] = *(const f32x4*)(pb + 4);
        }
        u32x4 wa[4], wb[4];
#pragma unroll
        for (int it = 0; it < 4; ++it) {
            wa[it] = u32x4{pack2bf(ga[it][0][0], ga[it][0][1]),
                           pack2bf(ga[it][0][2], ga[it][0][3]),
                           pack2bf(ga[it][1][0], ga[it][1][1]),
                           pack2bf(ga[it][1][2], ga[it][1][3])};
            wb[it] = u32x4{pack2bf(gb[it][0][0], gb[it][0][1]),
                           pack2bf(gb[it][0][2], gb[it][0][3]),
                           pack2bf(gb[it][1][0], gb[it][1][1]),
                           pack2bf(gb[it][1][2], gb[it][1][3])};
        }
        __syncthreads();
#pragma unroll
        for (int it = 0; it < 4; ++it) {
            *(u32x4*)&sA[tid * 8 + it * 2048] = wa[it];
            *(u32x4*)&sB[tid * 8 + it * 2048] = wb[it];
        }
        __syncthreads();
#pragma unroll
        for (int ks = 0; ks < 64; ks += 32) {
            bf16x8 af[4], bfr[4];
#pragma unroll
            for (int mi = 0; mi < 4; ++mi)
                af[mi] = *(const bf16x8*)&sA[(aRow + mi * 16) * 64 + ks + kOff];
#pragma unroll
            for (int ni = 0; ni < 4; ++ni)
                bfr[ni] = *(const bf16x8*)&sB[(bRow + ni * 16) * 64 + ks + kOff];
#pragma unroll
            for (int mi = 0; mi < 4; ++mi)
#pragma unroll
                for (int ni = 0; ni < 4; ++ni)
                    acc[mi][ni] = __builtin_amdgcn_mfma_f32_16x16x32_bf16(
                        af[mi], bfr[ni], acc[mi][ni], 0, 0, 0);
        }
    }
    const int colBase = bn * 128 + wn * 64 + l16;
    const int rowBase = bm * 128 + wm * 64 + quad * 4;
#pragma unroll
    for (int ni = 0; ni < 4; ++ni) {
        const int col = colBase + ni * 16;
        const float bv = bias[col];
#pragma unroll
        for (int mi = 0; mi < 4; ++mi) {
            const int row = rowBase + mi * 16;
#pragma unroll
            for (int r = 0; r < 4; ++r)
                C[(size_t)(row + r) * N_DIM + col] = acc[mi][ni][r] + bv;
        }
    }
}

extern "C" void kernel_launch(void* const* d_in, const int* in_sizes, int n_in,
                              void* d_out, int out_size, void* d_ws, size_t ws_size,
                              hipStream_t stream) {
    const float* x = (const float*)d_in[0];   // [8192, 4096]
    const float* w = (const float*)d_in[1];   // [4096, 4096]
    const float* b = (const float*)d_in[2];   // [4096]
    float* out = (float*)d_out;

    if (ws_size >= A_PACK_BYTES + W_PACK_BYTES) {
        u32x4* aP = (u32x4*)d_ws;
        u32x4* wP = (u32x4*)((char*)d_ws + A_PACK_BYTES);
        const int total_chunks = A_CHUNKS + W_CHUNKS;
        pack_bf16_kernel<<<total_chunks / 256, 256, 0, stream>>>(x, w, aP, wP);
        dim3 grid(N_DIM / BN, M_DIM / BM);    // (32, 64) = 2048 blocks
        gemm_packed_kernel<<<grid, 256, 0, stream>>>(
            (const u16*)aP, (const u16*)wP, b, out);
    } else {
        dim3 grid(N_DIM / 128, M_DIM / 128);
        linear_f32_bf16mfma_kernel<<<grid, 256, 0, stream>>>(x, w, b, out);
    }
}